// Round 4
// baseline (194.342 us; speedup 1.0000x reference)
//
#include <hip/hip_runtime.h>
#include <math.h>

#define N      4096
#define NIMG   2048
#define SPAN   256           // staged x-span per strip (64 lanes x 4 cols)
#define TXN    248           // net output cols per strip
#define HR     16            // output rows per strip
#define DRS    24            // D rows per strip = HR + 8
#define IPP    15            // img patch pitch (odd -> 2-bank stride, conflict-free)
#define IPR    130           // img patch rows (256-span/2 + 2)
#define IPOFF  1952          // float4-aligned VX offset (>= IPR*IPP = 1950)
#define WSZ    (IPOFF + 512) // per-wave LDS floats (patch + 2 exchange slots)
#define NSX    17            // ceil(4096/248)
#define NSY    256           // 4096/16
#define NSTRIP (NSX * NSY)   // 4352 wave-strips
#define NBLK   ((NSTRIP + 3) / 4)

// Gaussian kernel sigma=1, r=4 (double-precision eval of reference formula)
#define KW0 0.00013383063f
#define KW1 0.00443186160f
#define KW2 0.05399112800f
#define KW3 0.24197144000f
#define KW4 0.39894346870f

__device__ __forceinline__ int symi(int g) {
    g = (g < 0) ? (-1 - g) : g;
    g = (g >= N) ? (2 * N - 1 - g) : g;
    return g;
}

// 9-tap symmetric blur (vertical and horizontal both use this)
#define H9(A,B,C,D,E,F,G,H,I)                                                  \
    fmaf(KW0,(A), fmaf(KW1,(B), fmaf(KW2,(C), fmaf(KW3,(D), fmaf(KW4,(E),     \
    fmaf(KW3,(F), fmaf(KW2,(G), fmaf(KW1,(H), KW0*(I)))))))))

// fast path: 4 bilinear-x g values (one per lane col) for img column J.
// lane's 4 cols map to img rows {m,m-1,m-1,m-2} with alternating 0.25/0.75.
#define GCOL(J, G) do {                                                        \
    const float p0_ = IP[ipb - 2*IPP + (J)];                                   \
    const float p1_ = IP[ipb -   IPP + (J)];                                   \
    const float p2_ = IP[ipb         + (J)];                                   \
    const float p3_ = IP[ipb +   IPP + (J)];                                   \
    (G).x = fmaf(0.75f, p2_, 0.25f * p3_);                                     \
    (G).y = fmaf(0.25f, p1_, 0.75f * p2_);                                     \
    (G).z = fmaf(0.75f, p1_, 0.25f * p2_);                                     \
    (G).w = fmaf(0.25f, p0_, 0.75f * p1_);                                     \
} while (0)

#define DMIX(DST, W0, GA_, W1, GB_, NZ) do {                                   \
    (DST).x = fmaf(W0, (GA_).x, fmaf(W1, (GB_).x, 0.01f * (NZ).x));            \
    (DST).y = fmaf(W0, (GA_).y, fmaf(W1, (GB_).y, 0.01f * (NZ).y));            \
    (DST).z = fmaf(W0, (GA_).z, fmaf(W1, (GB_).z, 0.01f * (NZ).z));            \
    (DST).w = fmaf(W0, (GA_).w, fmaf(W1, (GB_).w, 0.01f * (NZ).w));            \
} while (0)

// fast produce: 4 D rows using g-col carry (ga,gb) + 2 fresh g-cols (JN,JN+1)
#define PROD4F(JN, W0_, W1_, W2_, W3_, Z0, Z1, Z2, Z3) do {                    \
    float4 gc_, gd_;                                                           \
    GCOL((JN), gc_);  GCOL((JN) + 1, gd_);                                     \
    DMIX(W0_, 0.25f, ga, 0.75f, gb,  Z0);                                      \
    DMIX(W1_, 0.75f, gb, 0.25f, gc_, Z1);                                      \
    DMIX(W2_, 0.25f, gb, 0.75f, gc_, Z2);                                      \
    DMIX(W3_, 0.75f, gc_, 0.25f, gd_, Z3);                                     \
    ga = gc_;  gb = gd_;                                                       \
} while (0)

// one output row: vblur from window (win[K..K+8]) -> float4 neighbor exchange
// via wave-private LDS (in-order DS, 2 alternating slots) -> hblur -> store
#define OUT1(K, GY) do {                                                       \
    float4 v_;                                                                 \
    v_.x = H9(win[K].x, win[K+1].x, win[K+2].x, win[K+3].x, win[K+4].x,        \
              win[K+5].x, win[K+6].x, win[K+7].x, win[K+8].x);                 \
    v_.y = H9(win[K].y, win[K+1].y, win[K+2].y, win[K+3].y, win[K+4].y,        \
              win[K+5].y, win[K+6].y, win[K+7].y, win[K+8].y);                 \
    v_.z = H9(win[K].z, win[K+1].z, win[K+2].z, win[K+3].z, win[K+4].z,        \
              win[K+5].z, win[K+6].z, win[K+7].z, win[K+8].z);                 \
    v_.w = H9(win[K].w, win[K+1].w, win[K+2].w, win[K+3].w, win[K+4].w,        \
              win[K+5].w, win[K+6].w, win[K+7].w, win[K+8].w);                 \
    float* vx_ = ((K) & 1) ? VX1 : VX0;                                        \
    *reinterpret_cast<float4*>(vx_ + 4 * lane) = v_;                           \
    const float4 wl_ = *reinterpret_cast<const float4*>(vx_ + 4 * lnL);        \
    const float4 wr_ = *reinterpret_cast<const float4*>(vx_ + 4 * lnR);        \
    float4 r_;                                                                 \
    r_.x = H9(wl_.x, wl_.y, wl_.z, wl_.w, v_.x, v_.y, v_.z, v_.w, wr_.x);      \
    r_.y = H9(wl_.y, wl_.z, wl_.w, v_.x, v_.y, v_.z, v_.w, wr_.x, wr_.y);      \
    r_.z = H9(wl_.z, wl_.w, v_.x, v_.y, v_.z, v_.w, wr_.x, wr_.y, wr_.z);      \
    r_.w = H9(wl_.w, v_.x, v_.y, v_.z, v_.w, wr_.x, wr_.y, wr_.z, wr_.w);      \
    r_.x = __logf(1.0f + fmaxf(r_.x, 0.0f));                                   \
    r_.y = __logf(1.0f + fmaxf(r_.y, 0.0f));                                   \
    r_.z = __logf(1.0f + fmaxf(r_.z, 0.0f));                                   \
    r_.w = __logf(1.0f + fmaxf(r_.w, 0.0f));                                   \
    if (okst) *reinterpret_cast<float4*>(out + (size_t)(GY) * N + gxs) = r_;   \
} while (0)

#define SLIDE4() do {                                                          \
    _Pragma("unroll")                                                          \
    for (int i_ = 0; i_ < 8; ++i_) win[i_] = win[i_ + 4];                      \
} while (0)

__global__ __launch_bounds__(256, 4)
void TensorAugment_79216376807666_kernel(const float* __restrict__ img,
                                         const float* __restrict__ noise,
                                         float* __restrict__ out) {
    __shared__ __align__(16) float SH[4 * WSZ];      // 39.4 KB

    const int tid  = threadIdx.x;
    const int lane = tid & 63;
    const int wave = tid >> 6;

    float* const IP  = SH + wave * WSZ;
    float* const VX0 = IP + IPOFF;
    float* const VX1 = VX0 + 256;

    const int strip0 = blockIdx.x * 4 + wave;
    if (strip0 >= NSTRIP) return;                    // whole-wave exit; no barriers

    const int strip = __builtin_amdgcn_readfirstlane(strip0);
    const int sx = strip % NSX;
    const int sy = strip / NSX;
    const int x0 = sx * TXN;
    const int y0 = sy * HR;
    const bool xin = (sx > 0) && (sx < NSX - 1);     // no x reflection in span
    const bool yin = (sy > 0) && (sy < NSY - 1);     // no y reflection in D rows

    // ---- wave-uniform staged img ranges (x -> img rows, y -> img cols) ----
    int gxa = x0 - 4, gxb = x0 + SPAN - 5;
    int mxa = symi(gxa), mxb = symi(gxb);
    int gxmin = min(mxa, mxb), gxmax = max(mxa, mxb);
    if (gxa <= 0) gxmin = 0;
    if (gxb >= N - 1) gxmax = N - 1;
    int umin = (N - 1) - gxmax, umax = (N - 1) - gxmin;
    int r0min = (umin - 1) >> 1;
    int r0max = (umax - 1) >> 1;
    int nrows = r0max - r0min + 2;                   // <= 130

    int gya = y0 - 4, gyb = y0 + DRS - 5;
    int mya = symi(gya), myb = symi(gyb);
    int gymin = min(mya, myb), gymax = max(mya, myb);
    if (gya <= 0) gymin = 0;
    if (gyb >= N - 1) gymax = N - 1;
    int c0min = (gymin - 1) >> 1;
    int c0max = (gymax - 1) >> 1;
    int ncols = c0max - c0min + 2;                   // <= 14

    // ---- stage img patch (wave-private; same-wave DS ops are in-order) ----
    {
        const int c  = lane & 15;
        const int rb = lane >> 4;
        const bool cok = (c < ncols);
#pragma unroll
        for (int k = 0; k < 33; ++k) {
            const int r = rb + 4 * k;
            if (cok && r < nrows) {
                const int ir = min(max(r0min + r, 0), NIMG - 1);
                const int ic = min(max(c0min + c, 0), NIMG - 1);
                IP[r * IPP + c] = img[ir * NIMG + ic];
            }
        }
    }

    const int gxs  = x0 - 4 + 4 * lane;              // first of this lane's 4 cols
    const bool okst = (lane >= 1) && (lane <= 62) && (gxs <= N - 4);
    const int lnL = (lane == 0) ? 0 : lane - 1;
    const int lnR = (lane == 63) ? 63 : lane + 1;

    if (xin && yin) {
        // ================= fast path (93% of strips) =================
        const int m   = 2049 - (x0 >> 1) - 2 * lane; // img row of col0's r0
        const int ipb = (m - r0min) * IPP;
        const float* const nzb = noise + ((size_t)(y0 - 4) * N + gxs);
#define LDNZ(DR) (*reinterpret_cast<const float4*>(nzb + (size_t)(DR) * N))

        float4 win[12];
        float4 ga, gb;
        GCOL(0, ga);
        GCOL(1, gb);

        // prologue: D rows 0..11
        {
            float4 n0 = LDNZ(0), n1 = LDNZ(1), n2 = LDNZ(2), n3 = LDNZ(3);
            float4 n4 = LDNZ(4), n5 = LDNZ(5), n6 = LDNZ(6), n7 = LDNZ(7);
            PROD4F(2, win[0], win[1], win[2], win[3], n0, n1, n2, n3);
            float4 n8 = LDNZ(8), n9 = LDNZ(9), na = LDNZ(10), nb = LDNZ(11);
            PROD4F(4, win[4], win[5], win[6], win[7], n4, n5, n6, n7);
            PROD4F(6, win[8], win[9], win[10], win[11], n8, n9, na, nb);
        }
        // chunk 0: out rows 0..3, produce D 12..15
        {
            float4 n0 = LDNZ(12), n1 = LDNZ(13), n2 = LDNZ(14), n3 = LDNZ(15);
            OUT1(0, y0 + 0);  OUT1(1, y0 + 1);  OUT1(2, y0 + 2);  OUT1(3, y0 + 3);
            SLIDE4();
            PROD4F(8, win[8], win[9], win[10], win[11], n0, n1, n2, n3);
        }
        // chunk 1: out rows 4..7, produce D 16..19
        {
            float4 n0 = LDNZ(16), n1 = LDNZ(17), n2 = LDNZ(18), n3 = LDNZ(19);
            OUT1(0, y0 + 4);  OUT1(1, y0 + 5);  OUT1(2, y0 + 6);  OUT1(3, y0 + 7);
            SLIDE4();
            PROD4F(10, win[8], win[9], win[10], win[11], n0, n1, n2, n3);
        }
        // chunk 2: out rows 8..11, produce D 20..23
        {
            float4 n0 = LDNZ(20), n1 = LDNZ(21), n2 = LDNZ(22), n3 = LDNZ(23);
            OUT1(0, y0 + 8);  OUT1(1, y0 + 9);  OUT1(2, y0 + 10); OUT1(3, y0 + 11);
            SLIDE4();
            PROD4F(12, win[8], win[9], win[10], win[11], n0, n1, n2, n3);
        }
        // chunk 3: out rows 12..15
        OUT1(0, y0 + 12); OUT1(1, y0 + 13); OUT1(2, y0 + 14); OUT1(3, y0 + 15);
#undef LDNZ
    } else {
        // ================= generic edge path (~7% of strips) =================
        const int gxm0 = symi(gxs + 0), gxm1 = symi(gxs + 1);
        const int gxm2 = symi(gxs + 2), gxm3 = symi(gxs + 3);
        const int u0 = (N - 1) - gxm0, u1 = (N - 1) - gxm1;
        const int u2 = (N - 1) - gxm2, u3 = (N - 1) - gxm3;
        const int A0 = (((u0 - 1) >> 1) - r0min) * IPP;
        const int A1 = (((u1 - 1) >> 1) - r0min) * IPP;
        const int A2 = (((u2 - 1) >> 1) - r0min) * IPP;
        const int A3 = (((u3 - 1) >> 1) - r0min) * IPP;
        const float w10 = (u0 & 1) ? 0.25f : 0.75f, w00 = 1.0f - w10;
        const float w11 = (u1 & 1) ? 0.25f : 0.75f, w01 = 1.0f - w11;
        const float w12 = (u2 & 1) ? 0.25f : 0.75f, w02 = 1.0f - w12;
        const float w13 = (u3 & 1) ? 0.25f : 0.75f, w03 = 1.0f - w13;

        auto nzg = [&](int dr) -> float4 {
            const float* nr = noise + (size_t)symi(y0 - 4 + dr) * N;
            float4 r;
            r.x = nr[gxm0]; r.y = nr[gxm1]; r.z = nr[gxm2]; r.w = nr[gxm3];
            return r;
        };
        auto dgen = [&](int dr, float4 nz) -> float4 {
            const int gym = symi(y0 - 4 + dr);
            const int jc  = ((gym - 1) >> 1) - c0min;
            const float wc1 = (gym & 1) ? 0.25f : 0.75f;
            const float wc0 = 1.0f - wc1;
            float4 r;
            {
                const float t = fmaf(wc0, IP[A0 + jc], wc1 * IP[A0 + jc + 1]);
                const float b = fmaf(wc0, IP[A0 + IPP + jc], wc1 * IP[A0 + IPP + jc + 1]);
                r.x = fmaf(w00, t, fmaf(w10, b, 0.01f * nz.x));
            }
            {
                const float t = fmaf(wc0, IP[A1 + jc], wc1 * IP[A1 + jc + 1]);
                const float b = fmaf(wc0, IP[A1 + IPP + jc], wc1 * IP[A1 + IPP + jc + 1]);
                r.y = fmaf(w01, t, fmaf(w11, b, 0.01f * nz.y));
            }
            {
                const float t = fmaf(wc0, IP[A2 + jc], wc1 * IP[A2 + jc + 1]);
                const float b = fmaf(wc0, IP[A2 + IPP + jc], wc1 * IP[A2 + IPP + jc + 1]);
                r.z = fmaf(w02, t, fmaf(w12, b, 0.01f * nz.z));
            }
            {
                const float t = fmaf(wc0, IP[A3 + jc], wc1 * IP[A3 + jc + 1]);
                const float b = fmaf(wc0, IP[A3 + IPP + jc], wc1 * IP[A3 + IPP + jc + 1]);
                r.w = fmaf(w03, t, fmaf(w13, b, 0.01f * nz.w));
            }
            return r;
        };

        float4 win[12];
#pragma unroll
        for (int j = 0; j < 12; ++j) win[j] = dgen(j, nzg(j));

#pragma unroll
        for (int c = 0; c < 4; ++c) {
            float4 n0, n1, n2, n3;
            if (c < 3) { n0 = nzg(12 + 4*c); n1 = nzg(13 + 4*c);
                         n2 = nzg(14 + 4*c); n3 = nzg(15 + 4*c); }
            OUT1(0, y0 + 4*c + 0);  OUT1(1, y0 + 4*c + 1);
            OUT1(2, y0 + 4*c + 2);  OUT1(3, y0 + 4*c + 3);
            if (c < 3) {
                SLIDE4();
                win[8]  = dgen(12 + 4*c, n0);
                win[9]  = dgen(13 + 4*c, n1);
                win[10] = dgen(14 + 4*c, n2);
                win[11] = dgen(15 + 4*c, n3);
            }
        }
    }
}

extern "C" void kernel_launch(void* const* d_in, const int* in_sizes, int n_in,
                              void* d_out, int out_size, void* d_ws, size_t ws_size,
                              hipStream_t stream) {
    const float* img   = (const float*)d_in[0];   // (1, 2048, 2048) f32
    const float* noise = (const float*)d_in[1];   // (1, 4096, 4096) f32
    float* out = (float*)d_out;                   // (1, 4096, 4096) f32

    dim3 grid(NBLK);                              // 1088 blocks x 256 (4 wave-strips each)
    TensorAugment_79216376807666_kernel<<<grid, 256, 0, stream>>>(img, noise, out);
}

// Round 5
// 140.614 us; speedup vs baseline: 1.3821x; 1.3821x over previous
//
#include <hip/hip_runtime.h>
#include <math.h>

#define N      4096
#define NIMG   2048
#define SPAN   128           // staged x-cols per block (64 lanes x float2)
#define TXN    120           // net output cols per block
#define HRW    16            // output rows per wave (block = 64 rows)
#define PP     66            // img patch pitch (banks stride 2 -> 2-way, free)
#define PR     66            // img patch rows (span/2 + 2)
#define NSX    35            // ceil(4096/120)
#define NSY    64            // 4096/64
#define NBLK   (NSX * NSY)   // 2240 blocks

// Gaussian kernel sigma=1, r=4 (double-precision eval of reference formula)
#define KW0 0.00013383063f
#define KW1 0.00443186160f
#define KW2 0.05399112800f
#define KW3 0.24197144000f
#define KW4 0.39894346870f

__device__ __forceinline__ int symi(int g) {
    g = (g < 0) ? (-1 - g) : g;
    g = (g >= N) ? (2 * N - 1 - g) : g;
    return g;
}

#define H9(A,B,C,D,E,F,G,H,I)                                                  \
    fmaf(KW0,(A), fmaf(KW1,(B), fmaf(KW2,(C), fmaf(KW3,(D), fmaf(KW4,(E),      \
    fmaf(KW3,(F), fmaf(KW2,(G), fmaf(KW1,(H), KW0*(I)))))))))

// g-column J (abs staged col): bilinear-x for this lane's 2 output cols.
// even col x=2a: 0.75*I[2047-a] + 0.25*I[2048-a]; odd: 0.25*I[2046-a] + 0.75*I[2047-a]
#define GCOL2(J, G) do {                                                       \
    const float p0_ = ipg[(J) - PP];                                           \
    const float p1_ = ipg[(J)];                                                \
    const float p2_ = ipg[(J) + PP];                                           \
    (G).x = fmaf(0.75f, p1_, 0.25f * p2_);                                     \
    (G).y = fmaf(0.25f, p0_, 0.75f * p1_);                                     \
} while (0)

// 4 D rows from carried g-cols (ga,gb) + 2 fresh (J2, J2+1); weights follow
// the verified R3 interior pattern: (.25,.75)(.75,.25)(.25,.75)(.75,.25)
#define PROD4(J2, D0, D1, D2, D3, Z0, Z1, Z2, Z3) do {                         \
    float2 gc_, gd_;                                                           \
    GCOL2((J2), gc_); GCOL2((J2) + 1, gd_);                                    \
    (D0).x = fmaf(0.25f, ga.x, fmaf(0.75f, gb.x, 0.01f * (Z0).x));             \
    (D0).y = fmaf(0.25f, ga.y, fmaf(0.75f, gb.y, 0.01f * (Z0).y));             \
    (D1).x = fmaf(0.75f, gb.x, fmaf(0.25f, gc_.x, 0.01f * (Z1).x));            \
    (D1).y = fmaf(0.75f, gb.y, fmaf(0.25f, gc_.y, 0.01f * (Z1).y));            \
    (D2).x = fmaf(0.25f, gb.x, fmaf(0.75f, gc_.x, 0.01f * (Z2).x));            \
    (D2).y = fmaf(0.25f, gb.y, fmaf(0.75f, gc_.y, 0.01f * (Z2).y));            \
    (D3).x = fmaf(0.75f, gc_.x, fmaf(0.25f, gd_.x, 0.01f * (Z3).x));           \
    (D3).y = fmaf(0.75f, gc_.y, fmaf(0.25f, gd_.y, 0.01f * (Z3).y));           \
    ga = gc_; gb = gd_;                                                        \
} while (0)

// one output row: vblur (registers) -> float2 LDS exchange (wave-private,
// in-order DS, alternating slots) -> hblur -> relu/log1p -> float2 store
#define OUT1(K, GY) do {                                                       \
    float2 v_;                                                                 \
    v_.x = H9(win[K].x, win[K+1].x, win[K+2].x, win[K+3].x, win[K+4].x,        \
              win[K+5].x, win[K+6].x, win[K+7].x, win[K+8].x);                 \
    v_.y = H9(win[K].y, win[K+1].y, win[K+2].y, win[K+3].y, win[K+4].y,        \
              win[K+5].y, win[K+6].y, win[K+7].y, win[K+8].y);                 \
    float* sl_ = ((K) & 1) ? EX1 : EX0;                                        \
    *reinterpret_cast<float2*>(sl_ + 2 * lane) = v_;                           \
    const float2 l0_ = *reinterpret_cast<const float2*>(sl_ + oL0);            \
    const float2 l1_ = *reinterpret_cast<const float2*>(sl_ + oL1);            \
    const float2 r0_ = *reinterpret_cast<const float2*>(sl_ + oR0);            \
    const float2 r1_ = *reinterpret_cast<const float2*>(sl_ + oR1);            \
    float ox_ = KW0 * l0_.x; ox_ = fmaf(KW1, l0_.y, ox_);                      \
    ox_ = fmaf(KW2, l1_.x, ox_); ox_ = fmaf(KW3, l1_.y, ox_);                  \
    ox_ = fmaf(KW4, v_.x, ox_);  ox_ = fmaf(KW3, v_.y, ox_);                   \
    ox_ = fmaf(KW2, r0_.x, ox_); ox_ = fmaf(KW1, r0_.y, ox_);                  \
    ox_ = fmaf(KW0, r1_.x, ox_);                                               \
    float oy_ = KW0 * l0_.y; oy_ = fmaf(KW1, l1_.x, oy_);                      \
    oy_ = fmaf(KW2, l1_.y, oy_); oy_ = fmaf(KW3, v_.x, oy_);                   \
    oy_ = fmaf(KW4, v_.y, oy_);  oy_ = fmaf(KW3, r0_.x, oy_);                  \
    oy_ = fmaf(KW2, r0_.y, oy_); oy_ = fmaf(KW1, r1_.x, oy_);                  \
    oy_ = fmaf(KW0, r1_.y, oy_);                                               \
    float2 rr_;                                                                \
    rr_.x = __logf(1.0f + fmaxf(ox_, 0.0f));                                   \
    rr_.y = __logf(1.0f + fmaxf(oy_, 0.0f));                                   \
    if (okst) *reinterpret_cast<float2*>(out + (size_t)(GY) * N + gxs) = rr_;  \
} while (0)

#define SLIDE4() do {                                                          \
    _Pragma("unroll")                                                          \
    for (int i_ = 0; i_ < 8; ++i_) win[i_] = win[i_ + 4];                      \
} while (0)

__global__ __launch_bounds__(256, 5)
void TensorAugment_79216376807666_kernel(const float* __restrict__ img,
                                         const float* __restrict__ noise,
                                         float* __restrict__ out) {
    __shared__ __align__(16) float SH[PR * PP + 4 * 256];    // 21.5 KB

    const int tid  = threadIdx.x;
    const int lane = tid & 63;
    const int wave = tid >> 6;

    float* const IP  = SH;
    float* const EX0 = SH + PR * PP + wave * 256;
    float* const EX1 = EX0 + 128;

    const int bid = blockIdx.x;
    const int sx  = bid % NSX;
    const int sy  = bid / NSX;
    const int x0  = sx * TXN;                        // staged cols x0-4 .. x0+123
    const int y0  = sy * 64;                         // block output rows y0..y0+63

    // ---- block-uniform staged img ranges (x -> img rows, y -> img cols) ----
    int gxa = x0 - 4, gxb = x0 + SPAN - 5;
    int mxa = symi(gxa), mxb = symi(gxb);
    int gxmin = min(mxa, mxb), gxmax = max(mxa, mxb);
    if (gxa <= 0) gxmin = 0;
    if (gxb >= N - 1) gxmax = N - 1;
    int umin = (N - 1) - gxmax, umax = (N - 1) - gxmin;
    int r0min = (umin - 1) >> 1;
    int r0max = (umax - 1) >> 1;
    int nrows = r0max - r0min + 2;                   // <= 66

    int gya = y0 - 4, gyb = y0 + 67;                 // block D rows y0-4 .. y0+67
    int mya = symi(gya), myb = symi(gyb);
    int gymin = min(mya, myb), gymax = max(mya, myb);
    if (gya <= 0) gymin = 0;
    if (gyb >= N - 1) gymax = N - 1;
    int c0min = (gymin - 1) >> 1;                    // clamped cols replicate
    // jax resize edge-extend semantics (verified R2-R4)

    // ---- cooperative patch staging: lane = col, coalesced 256B per row ----
    {
        const int gcol = min(max(c0min + lane, 0), NIMG - 1);
        for (int r = wave; r < nrows; r += 4) {
            const int ir = min(max(r0min + r, 0), NIMG - 1);
            IP[r * PP + lane] = img[ir * NIMG + gcol];   // banks stride 1: free
        }
    }
    __syncthreads();                                  // the only barrier

    // ---- per-wave / per-lane setup ----
    const int y0w = y0 + HRW * wave;
    const int gxs = x0 - 4 + 2 * lane;               // lane's first output col
    const bool okst = (lane >= 2) && (lane <= 61) && (gxs <= N - 2);
    const bool yin  = (y0w >= 4) && (y0w + 19 <= N - 1);
    const bool xin  = (sx > 0) && (sx < NSX - 1);
    const int oL0 = max(2 * lane - 4, 0), oL1 = max(2 * lane - 2, 0);
    const int oR0 = min(2 * lane + 2, 126), oR1 = min(2 * lane + 4, 126);

    float2 win[12];

    if (xin && yin) {
        // ================= fast path =================
        const int a    = (x0 >> 1) - 2 + lane;       // gxs = 2a
        const int ipb  = (2047 - a - r0min) * PP;
        const float* const ipg = IP + ipb;
        const int jb   = ((y0w - 5) >> 1) - c0min;   // wave's g-col base
        const float* const nzb = noise + ((size_t)(y0w - 4) * N + gxs);
#define LDNZ(DR) (*reinterpret_cast<const float2*>(nzb + (size_t)(DR) * N))

        float2 ga, gb;
        GCOL2(jb, ga);
        GCOL2(jb + 1, gb);

        // prologue: D rows 0..11
        {
            float2 n0 = LDNZ(0), n1 = LDNZ(1), n2 = LDNZ(2),  n3 = LDNZ(3);
            float2 n4 = LDNZ(4), n5 = LDNZ(5), n6 = LDNZ(6),  n7 = LDNZ(7);
            float2 n8 = LDNZ(8), n9 = LDNZ(9), na = LDNZ(10), nb = LDNZ(11);
            PROD4(jb + 2, win[0], win[1], win[2],  win[3],  n0, n1, n2, n3);
            PROD4(jb + 4, win[4], win[5], win[6],  win[7],  n4, n5, n6, n7);
            PROD4(jb + 6, win[8], win[9], win[10], win[11], n8, n9, na, nb);
        }
        // chunk 0: out rows y0w..+3, produce D 12..15
        {
            float2 n0 = LDNZ(12), n1 = LDNZ(13), n2 = LDNZ(14), n3 = LDNZ(15);
            OUT1(0, y0w + 0); OUT1(1, y0w + 1); OUT1(2, y0w + 2); OUT1(3, y0w + 3);
            SLIDE4();
            PROD4(jb + 8, win[8], win[9], win[10], win[11], n0, n1, n2, n3);
        }
        // chunk 1: out rows +4..7, produce D 16..19
        {
            float2 n0 = LDNZ(16), n1 = LDNZ(17), n2 = LDNZ(18), n3 = LDNZ(19);
            OUT1(0, y0w + 4); OUT1(1, y0w + 5); OUT1(2, y0w + 6); OUT1(3, y0w + 7);
            SLIDE4();
            PROD4(jb + 10, win[8], win[9], win[10], win[11], n0, n1, n2, n3);
        }
        // chunk 2: out rows +8..11, produce D 20..23
        {
            float2 n0 = LDNZ(20), n1 = LDNZ(21), n2 = LDNZ(22), n3 = LDNZ(23);
            OUT1(0, y0w + 8); OUT1(1, y0w + 9); OUT1(2, y0w + 10); OUT1(3, y0w + 11);
            SLIDE4();
            PROD4(jb + 12, win[8], win[9], win[10], win[11], n0, n1, n2, n3);
        }
        // chunk 3: out rows +12..15
        OUT1(0, y0w + 12); OUT1(1, y0w + 13); OUT1(2, y0w + 14); OUT1(3, y0w + 15);
#undef LDNZ
    } else {
        // ================= generic edge path =================
        const int gxm0 = symi(gxs), gxm1 = symi(gxs + 1);
        const int u0 = (N - 1) - gxm0, u1 = (N - 1) - gxm1;
        const int A0 = (((u0 - 1) >> 1) - r0min) * PP;
        const int A1 = (((u1 - 1) >> 1) - r0min) * PP;
        const float w10 = (u0 & 1) ? 0.25f : 0.75f, w00 = 1.0f - w10;
        const float w11 = (u1 & 1) ? 0.25f : 0.75f, w01 = 1.0f - w11;

        auto nzg = [&](int dr) -> float2 {
            const float* nr = noise + (size_t)symi(y0w - 4 + dr) * N;
            float2 r; r.x = nr[gxm0]; r.y = nr[gxm1]; return r;
        };
        auto dgen = [&](int dr, float2 nz) -> float2 {
            const int gym = symi(y0w - 4 + dr);
            const int jc  = ((gym - 1) >> 1) - c0min;
            const float wc1 = (gym & 1) ? 0.25f : 0.75f;
            const float wc0 = 1.0f - wc1;
            float2 r;
            {
                const float t = fmaf(wc0, IP[A0 + jc], wc1 * IP[A0 + jc + 1]);
                const float b = fmaf(wc0, IP[A0 + PP + jc], wc1 * IP[A0 + PP + jc + 1]);
                r.x = fmaf(w00, t, fmaf(w10, b, 0.01f * nz.x));
            }
            {
                const float t = fmaf(wc0, IP[A1 + jc], wc1 * IP[A1 + jc + 1]);
                const float b = fmaf(wc0, IP[A1 + PP + jc], wc1 * IP[A1 + PP + jc + 1]);
                r.y = fmaf(w01, t, fmaf(w11, b, 0.01f * nz.y));
            }
            return r;
        };

#pragma unroll
        for (int j = 0; j < 12; ++j) win[j] = dgen(j, nzg(j));

#pragma unroll
        for (int c = 0; c < 4; ++c) {
            float2 n0, n1, n2, n3;
            if (c < 3) { n0 = nzg(12 + 4 * c); n1 = nzg(13 + 4 * c);
                         n2 = nzg(14 + 4 * c); n3 = nzg(15 + 4 * c); }
            OUT1(0, y0w + 4 * c + 0); OUT1(1, y0w + 4 * c + 1);
            OUT1(2, y0w + 4 * c + 2); OUT1(3, y0w + 4 * c + 3);
            if (c < 3) {
                SLIDE4();
                win[8]  = dgen(12 + 4 * c, n0);
                win[9]  = dgen(13 + 4 * c, n1);
                win[10] = dgen(14 + 4 * c, n2);
                win[11] = dgen(15 + 4 * c, n3);
            }
        }
    }
}

extern "C" void kernel_launch(void* const* d_in, const int* in_sizes, int n_in,
                              void* d_out, int out_size, void* d_ws, size_t ws_size,
                              hipStream_t stream) {
    const float* img   = (const float*)d_in[0];   // (1, 2048, 2048) f32
    const float* noise = (const float*)d_in[1];   // (1, 4096, 4096) f32
    float* out = (float*)d_out;                   // (1, 4096, 4096) f32

    dim3 grid(NBLK);                              // 2240 blocks x 256
    TensorAugment_79216376807666_kernel<<<grid, 256, 0, stream>>>(img, noise, out);
}